// Round 4
// baseline (37.969 us; speedup 1.0000x reference)
//
#include <hip/hip_runtime.h>
#include <hip/hip_bf16.h>

// Problem: in_frame [B=4, C=3, H=512, W=512] float32, scale = 4.
// out [4, 3, 2048, 2048] float32, out[b,c,ho,wo] = in[b,c,ho/4,wo/4].
//
// One thread per INPUT pixel p (exact grid):
//   wi = p & 511, rest = p >> 9  (rest = bc*512 + hi)
//   output float4-base = (4*rest)*512 + wi ; 4 rows, stride 512 float4.
//
// Stores are nontemporal (nt): 201 MB streaming output has zero reuse, so
// skip L2 write-allocate. __builtin_nontemporal_store needs a TRUE clang
// vector type (HIP's float4 is a struct) -> use ext_vector_type(4).
// Loads: coalesced, each input byte read exactly once (12.6 MB).

typedef float floatv4 __attribute__((ext_vector_type(4)));

__global__ void upscale4x_kernel(const float* __restrict__ in,
                                 float* __restrict__ out,
                                 int npix) {
    int p = blockIdx.x * blockDim.x + threadIdx.x;
    if (p >= npix) return;
    floatv4* __restrict__ out4 = reinterpret_cast<floatv4*>(out);

    int wi   = p & 511;
    int rest = p >> 9;               // bc*512 + hi
    float val = in[p];
    floatv4 v4 = {val, val, val, val};
    int base = (rest << 11) + wi;    // (4*rest)*512 + wi, in float4 units

    __builtin_nontemporal_store(v4, &out4[base]);
    __builtin_nontemporal_store(v4, &out4[base + 512]);
    __builtin_nontemporal_store(v4, &out4[base + 1024]);
    __builtin_nontemporal_store(v4, &out4[base + 1536]);
}

extern "C" void kernel_launch(void* const* d_in, const int* in_sizes, int n_in,
                              void* d_out, int out_size, void* d_ws, size_t ws_size,
                              hipStream_t stream) {
    const float* in = (const float*)d_in[0];
    float* out = (float*)d_out;

    int npix = in_sizes[0];          // 4*3*512*512 = 3145728

    const int block = 256;
    int grid = (npix + block - 1) / block;   // exact grid: 12288 blocks

    upscale4x_kernel<<<grid, block, 0, stream>>>(in, out, npix);
}

// Round 5
// 37.037 us; speedup vs baseline: 1.0252x; 1.0252x over previous
//
#include <hip/hip_runtime.h>
#include <hip/hip_bf16.h>

// Problem: in_frame [B=4, C=3, H=512, W=512] float32, scale = 4.
// out [4, 3, 2048, 2048] float32, out[b,c,ho,wo] = in[b,c,ho/4,wo/4].
//
// R2 structure (2048 blocks x 256 threads, regular float4 stores) + one
// change: the 6-iteration grid-stride loop is hard-unrolled with all 6
// independent loads issued up front (6x MLP per wave), then 24 stores.
// npix = 3145728 = 2048*256*6 exactly; threads stride by NT pixels so
// every load/store instruction stays fully coalesced (lane i adjacent).
//
// Per pixel p: wi = p & 511, rest = p >> 9 (= bc*512 + hi);
// output float4-base = (rest << 11) + wi; 4 rows at +512 float4 stride.

typedef float floatv4 __attribute__((ext_vector_type(4)));

__global__ void __launch_bounds__(256) upscale4x_kernel(
        const float* __restrict__ in,
        float* __restrict__ out) {
    const int NT = 2048 * 256;       // total threads = 524288
    int tid = blockIdx.x * 256 + threadIdx.x;
    floatv4* __restrict__ out4 = reinterpret_cast<floatv4*>(out);

    // 6 independent loads in flight
    float v[6];
#pragma unroll
    for (int j = 0; j < 6; ++j) {
        v[j] = in[tid + j * NT];
    }

#pragma unroll
    for (int j = 0; j < 6; ++j) {
        int p    = tid + j * NT;
        int wi   = p & 511;
        int rest = p >> 9;                   // bc*512 + hi
        int base = (rest << 11) + wi;        // float4 units
        floatv4 v4 = {v[j], v[j], v[j], v[j]};
        out4[base]        = v4;
        out4[base + 512]  = v4;
        out4[base + 1024] = v4;
        out4[base + 1536] = v4;
    }
}

extern "C" void kernel_launch(void* const* d_in, const int* in_sizes, int n_in,
                              void* d_out, int out_size, void* d_ws, size_t ws_size,
                              hipStream_t stream) {
    const float* in = (const float*)d_in[0];
    float* out = (float*)d_out;

    // npix = 3145728 = 2048 blocks * 256 threads * 6 px/thread (fixed shape)
    upscale4x_kernel<<<2048, 256, 0, stream>>>(in, out);
}